// Round 16
// baseline (217.298 us; speedup 1.0000x reference)
//
#include <hip/hip_runtime.h>
#include <hip/hip_bf16.h>

// RGCN regression: N=50000, E=800000, R=8, C=H=128.
// Round 16: R15 structure (202us, absmax 0.0078). Single change: agg output
// stores are NONTEMPORAL (nt-flagged dwordx4) — the 100MB/dispatch agg write
// stream was evicting the 12.8MB feature table from L2/L3 (agg FETCH 85MB vs
// 12.8MB table = 6.6x over-fetch). Bytes and numerics identical.

constexpr int NN = 50000;
constexpr int EE = 800000;
constexpr int NB = NN * 8;            // 400000 (dst,rel) buckets
constexpr int NCB = (NN + 255) >> 8;  // 196 coarse buckets
constexpr int EPB = 8192;             // edges per partition block
constexpr int PBLK = (EE + EPB - 1) / EPB;   // 98
constexpr int NSB = 2048;             // sub-buckets per coarse bucket

typedef __attribute__((ext_vector_type(8))) short bf16x8;
typedef __attribute__((ext_vector_type(16))) float f32x16;
typedef __attribute__((ext_vector_type(4))) uint u32x4;
typedef __attribute__((address_space(3))) uint32_t lds_u32;
typedef __attribute__((address_space(1))) const uint32_t glb_u32;

static __device__ __forceinline__ ushort f2bf(float f) {
    uint u = __float_as_uint(f);
    uint r = (u + 0x7fffu + ((u >> 16) & 1u)) >> 16;   // RTNE
    return (ushort)r;
}
static __device__ __forceinline__ float bflo(uint v) { return __uint_as_float(v << 16); }
static __device__ __forceinline__ float bfhi(uint v) { return __uint_as_float(v & 0xffff0000u); }

static __device__ __forceinline__ void stage16(const void* g, void* lds) {
    __builtin_amdgcn_global_load_lds((glb_u32*)g, (lds_u32*)lds, 16, 0, 0);
}

// ---------------- P1: coarse histogram (dst>>8), LDS-aggregated ----------------
__global__ __launch_bounds__(1024) void chist_kernel(const int* __restrict__ dst,
                                                     int* __restrict__ ghist) {
    __shared__ int h[NCB];
    const int t = threadIdx.x;
    for (int i = t; i < NCB; i += 1024) h[i] = 0;
    __syncthreads();
    const int e0 = blockIdx.x * EPB + t;
#pragma unroll
    for (int jj = 0; jj < 8; ++jj) {
        const int e = e0 + jj * 1024;
        if (e < EE) atomicAdd(&h[dst[e] >> 8], 1);
    }
    __syncthreads();
    for (int i = t; i < NCB; i += 1024)
        if (h[i]) atomicAdd(&ghist[i], h[i]);
}

// ---------------- P2: scan 196 coarse totals ----------------
__global__ __launch_bounds__(256) void cscan_kernel(const int* __restrict__ ghist,
                                                    int* __restrict__ gstart,
                                                    int* __restrict__ gcur) {
    __shared__ int sm[256];
    const int t = threadIdx.x;
    const int v = (t < NCB) ? ghist[t] : 0;
    sm[t] = v;
    __syncthreads();
    for (int d = 1; d < 256; d <<= 1) {
        int u = (t >= d) ? sm[t - d] : 0;
        __syncthreads();
        sm[t] += u;
        __syncthreads();
    }
    const int excl = sm[t] - v;
    if (t < NCB) { gstart[t] = excl; gcur[t] = excl; }
    if (t == NCB - 1) gstart[NCB] = excl + v;   // == EE
}

// ---------------- P3: coarse partition, block-reserved ranges ----------------
// packed = (dlow<<19) | (et<<16) | src
__global__ __launch_bounds__(1024) void cpart_kernel(const int* __restrict__ src,
                                                     const int* __restrict__ dst,
                                                     const int* __restrict__ et,
                                                     int* __restrict__ gcur,
                                                     uint* __restrict__ packed) {
    __shared__ int h[NCB];
    const int t = threadIdx.x;
    for (int i = t; i < NCB; i += 1024) h[i] = 0;
    __syncthreads();
    const int e0 = blockIdx.x * EPB + t;
    int myb[8]; uint mydat[8];
#pragma unroll
    for (int jj = 0; jj < 8; ++jj) {
        const int e = e0 + jj * 1024;
        if (e < EE) {
            const int d = dst[e];
            myb[jj] = d >> 8;
            mydat[jj] = (uint)src[e] | ((uint)et[e] << 16) | ((uint)(d & 255) << 19);
            atomicAdd(&h[myb[jj]], 1);
        } else myb[jj] = -1;
    }
    __syncthreads();
    for (int i = t; i < NCB; i += 1024)
        h[i] = h[i] ? atomicAdd(&gcur[i], h[i]) : 0;   // h becomes running cursor
    __syncthreads();
#pragma unroll
    for (int jj = 0; jj < 8; ++jj) {
        if (myb[jj] >= 0) {
            const int pos = atomicAdd(&h[myb[jj]], 1);
            packed[pos] = mydat[jj];
        }
    }
}

// ---------------- P4: per-coarse-bucket fine sort -> off[] + srcs[] ----------------
__global__ __launch_bounds__(1024) void fsort_kernel(const int* __restrict__ gstart,
                                                     const uint* __restrict__ packed,
                                                     int* __restrict__ off,
                                                     int* __restrict__ srcs) {
    __shared__ int hist[NSB];
    __shared__ int scn[NSB];
    __shared__ int h2[1024];
    const int b = blockIdx.x;
    const int t = threadIdx.x;
    const int s = gstart[b], e = gstart[b + 1];

    for (int i = t; i < NSB; i += 1024) hist[i] = 0;
    __syncthreads();
    for (int i = s + t; i < e; i += 1024)
        atomicAdd(&hist[(packed[i] >> 16) & 0x7FF], 1);
    __syncthreads();
    const int a0 = hist[2 * t], a1 = hist[2 * t + 1];
    h2[t] = a0 + a1;
    __syncthreads();
    for (int d = 1; d < 1024; d <<= 1) {
        int u = (t >= d) ? h2[t - d] : 0;
        __syncthreads();
        h2[t] += u;
        __syncthreads();
    }
    const int base = h2[t] - (a0 + a1);
    scn[2 * t] = base;
    scn[2 * t + 1] = base + a0;
    __syncthreads();
    const int gsubbase = b << 11;
    for (int i = t; i < NSB; i += 1024) {
        const int g = gsubbase + i;
        if (g < NB) off[g] = s + scn[i];
    }
    if (b == NCB - 1 && t == 0) off[NB] = EE;
    __syncthreads();
    for (int i = s + t; i < e; i += 1024) {
        const uint k = packed[i];
        const int pos = atomicAdd(&scn[(k >> 16) & 0x7FF], 1);
        srcs[s + pos] = (int)(k & 0xFFFF);
    }
}

// ---------------- x fp32 -> bf16 ----------------
__global__ __launch_bounds__(256) void cvt_x_kernel(const float* __restrict__ x,
                                                    ushort* __restrict__ xb) {
    const int tid = blockIdx.x * blockDim.x + threadIdx.x;
    const size_t i = (size_t)tid * 8;
    const float4 v0 = *reinterpret_cast<const float4*>(x + i);
    const float4 v1 = *reinterpret_cast<const float4*>(x + i + 4);
    uint4 o;
    o.x = (uint)f2bf(v0.x) | ((uint)f2bf(v0.y) << 16);
    o.y = (uint)f2bf(v0.z) | ((uint)f2bf(v0.w) << 16);
    o.z = (uint)f2bf(v1.x) | ((uint)f2bf(v1.y) << 16);
    o.w = (uint)f2bf(v1.z) | ((uint)f2bf(v1.w) << 16);
    *reinterpret_cast<uint4*>(xb + i) = o;
}

// ---------------- weights -> Bt[n][k] bf16, k = [root(128) | W(1024)] ----------------
__global__ __launch_bounds__(256) void prep_w_kernel(const float* __restrict__ root1,
                                                     const float* __restrict__ W1,
                                                     const float* __restrict__ root2,
                                                     const float* __restrict__ W2,
                                                     ushort* __restrict__ Bt1,
                                                     ushort* __restrict__ Bt2) {
    const float* root = blockIdx.y ? root2 : root1;
    const float* W    = blockIdx.y ? W2 : W1;
    ushort* Bt        = blockIdx.y ? Bt2 : Bt1;
    const int n = blockIdx.x;
    for (int k = threadIdx.x; k < 1152; k += 256) {
        float v = (k < 128) ? root[(size_t)k * 128 + n]
                            : W[(size_t)(k - 128) * 128 + n];
        Bt[(size_t)n * 1152 + k] = f2bf(v);
    }
}

// ---------------- aggregation: wave per node, 8 segments parallel, PIPELINED ----
// lane = g*8 + j. Index prefetch 2 ahead; feature-row prefetch 1 ahead.
// Output stores are NONTEMPORAL: keeps the 12.8MB feature table L2/L3-resident.
__global__ __launch_bounds__(256) void agg_kernel(const int* __restrict__ off,
                                                  const int* __restrict__ srcs,
                                                  const ushort* __restrict__ feat,
                                                  ushort* __restrict__ agg) {
    const int wid = (blockIdx.x * blockDim.x + threadIdx.x) >> 6;
    if (wid >= NN) return;
    const int lane = threadIdx.x & 63;
    const int g = lane >> 3;            // relation group 0..7
    const int j = lane & 7;             // 16-ushort chunk within row

    const int s1 = off[wid * 8 + g + 1];
    int i = off[wid * 8 + g];
    const int cnt = s1 - i;

    float a[16];
#pragma unroll
    for (int k = 0; k < 16; ++k) a[k] = 0.f;

    const size_t jb = (size_t)(j << 4);
    int p  = (i < s1)     ? srcs[i]     : 0;
    int pn = (i + 1 < s1) ? srcs[i + 1] : 0;
    const uint4* rp = reinterpret_cast<const uint4*>(feat + (size_t)p * 128 + jb);
    uint4 v0 = rp[0], v1 = rp[1];       // current row (empty-seg lanes read row 0: harmless)

    while (__any(i < s1)) {
        const int pnn = (i + 2 < s1) ? srcs[i + 2] : 0;     // index prefetch, 2 ahead
        const uint4* rn = reinterpret_cast<const uint4*>(feat + (size_t)pn * 128 + jb);
        const uint4 w0 = rn[0], w1 = rn[1];                 // row prefetch, 1 ahead
        if (i < s1) {
            a[0] += bflo(v0.x);  a[1] += bfhi(v0.x);
            a[2] += bflo(v0.y);  a[3] += bfhi(v0.y);
            a[4] += bflo(v0.z);  a[5] += bfhi(v0.z);
            a[6] += bflo(v0.w);  a[7] += bfhi(v0.w);
            a[8] += bflo(v1.x);  a[9] += bfhi(v1.x);
            a[10] += bflo(v1.y); a[11] += bfhi(v1.y);
            a[12] += bflo(v1.z); a[13] += bfhi(v1.z);
            a[14] += bflo(v1.w); a[15] += bfhi(v1.w);
        }
        v0 = w0; v1 = w1;
        p = pn; pn = pnn;
        ++i;
    }

    const float inv = 1.0f / (float)max(cnt, 1);
    u32x4 o0, o1;
    o0.x = (uint)f2bf(a[0] * inv)  | ((uint)f2bf(a[1] * inv)  << 16);
    o0.y = (uint)f2bf(a[2] * inv)  | ((uint)f2bf(a[3] * inv)  << 16);
    o0.z = (uint)f2bf(a[4] * inv)  | ((uint)f2bf(a[5] * inv)  << 16);
    o0.w = (uint)f2bf(a[6] * inv)  | ((uint)f2bf(a[7] * inv)  << 16);
    o1.x = (uint)f2bf(a[8] * inv)  | ((uint)f2bf(a[9] * inv)  << 16);
    o1.y = (uint)f2bf(a[10] * inv) | ((uint)f2bf(a[11] * inv) << 16);
    o1.z = (uint)f2bf(a[12] * inv) | ((uint)f2bf(a[13] * inv) << 16);
    o1.w = (uint)f2bf(a[14] * inv) | ((uint)f2bf(a[15] * inv) << 16);
    ushort* o = agg + (size_t)wid * 1024 + g * 128 + (j << 4);
    __builtin_nontemporal_store(o0, reinterpret_cast<u32x4*>(o));
    __builtin_nontemporal_store(o1, reinterpret_cast<u32x4*>(o) + 1);
}

// ---------------- MFMA GEMM: h = relu(bias + [xb|agg] @ Bt^T) ----------------
// A logical [N, 1152] bf16, Bt [128][1152] bf16. Block: 4 waves (2x2),
// tile 64(M) x 128(N), BK=64, 2-phase dbuf (R6, measured best).
// If outp != nullptr (layer 2): fused head — out[n] = relu(h[n]).Wout + bout
// computed from fp32 accs (shfl butterfly + LDS cross-wave add); hout unused.
__global__ __launch_bounds__(256) void gemm_mfma(const ushort* __restrict__ xb,
                                                 const ushort* __restrict__ agg,
                                                 const ushort* __restrict__ Bt,
                                                 const float* __restrict__ bias,
                                                 ushort* __restrict__ hout,
                                                 const float* __restrict__ Wout,
                                                 const float* __restrict__ bout,
                                                 float* __restrict__ outp) {
    __shared__ __align__(16) uint8_t smem[49152];
    const int t = threadIdx.x;
    const int lane = t & 63;
    const int w = t >> 6;
    const int wr = w >> 1, wc = w & 1;
    const int n0 = blockIdx.x * 64;
    const int l31 = lane & 31;
    const int lhalf = lane >> 5;

    f32x16 acc0, acc1;
#pragma unroll
    for (int r = 0; r < 16; ++r) { acc0[r] = 0.f; acc1[r] = 0.f; }

    const int rA = wr * 32 + l31;
    const int aoff = rA * 128, aswz = (rA & 7) << 4;
    const int nB0 = wc * 64 + l31;
    const int nB1 = nB0 + 32;
    const int boff0 = 8192 + nB0 * 128, bswz0 = (nB0 & 7) << 4;
    const int boff1 = 8192 + nB1 * 128, bswz1 = (nB1 & 7) << 4;
    const int ckb = lhalf << 4;

    const int rsub = lane >> 3;
    const int srcChunk = (((lane & 7) ^ (lane >> 3)) << 4);
    int garowA[2];
#pragma unroll
    for (int jj = 0; jj < 2; ++jj)
        garowA[jj] = min(n0 + 16 * w + 8 * jj + rsub, NN - 1);
    size_t bOffG[4];
#pragma unroll
    for (int jj = 0; jj < 4; ++jj)
        bOffG[jj] = (size_t)(32 * w + 8 * jj + rsub) * 2304 + srcChunk;

    const uint8_t* xb8  = (const uint8_t*)xb;
    const uint8_t* agg8 = (const uint8_t*)agg;
    const uint8_t* Bt8  = (const uint8_t*)Bt;

    auto STAGE = [&](int buf, int kt) {
        uint8_t* base = smem + buf * 24576;
        const uint8_t* Asrc; int shift, koffB;
        if (kt < 2) { Asrc = xb8;  shift = 8;  koffB = kt * 128; }
        else        { Asrc = agg8; shift = 11; koffB = (kt - 2) * 128; }
#pragma unroll
        for (int jj = 0; jj < 2; ++jj)
            stage16(Asrc + (((size_t)garowA[jj]) << shift) + koffB + srcChunk,
                    base + (2 * w + jj) * 1024);
#pragma unroll
        for (int jj = 0; jj < 4; ++jj)
            stage16(Bt8 + bOffG[jj] + kt * 128,
                    base + 8192 + (4 * w + jj) * 1024);
    };

    auto COMPUTE = [&](int buf) {
        const uint8_t* base = smem + buf * 24576;
#pragma unroll
        for (int kb = 0; kb < 4; ++kb) {
            const int cb = kb * 32 + ckb;
            const bf16x8 af = *reinterpret_cast<const bf16x8*>(base + aoff  + (cb ^ aswz));
            const bf16x8 b0 = *reinterpret_cast<const bf16x8*>(base + boff0 + (cb ^ bswz0));
            const bf16x8 b1 = *reinterpret_cast<const bf16x8*>(base + boff1 + (cb ^ bswz1));
            acc0 = __builtin_amdgcn_mfma_f32_32x32x16_bf16(af, b0, acc0, 0, 0, 0);
            acc1 = __builtin_amdgcn_mfma_f32_32x32x16_bf16(af, b1, acc1, 0, 0, 0);
        }
    };

    STAGE(0, 0);
    __syncthreads();
    int cur = 0;
#pragma unroll 1
    for (int kt = 0; kt < 17; ++kt) {
        STAGE(cur ^ 1, kt + 1);
        COMPUTE(cur);
        __syncthreads();
        cur ^= 1;
    }
    COMPUTE(cur);

    if (outp == nullptr) {
        // ---- layer 1 epilogue: write bf16 h ----
#pragma unroll
        for (int ni = 0; ni < 2; ++ni) {
            const int col = wc * 64 + ni * 32 + l31;
            const float bv = bias[col];
            const f32x16& a = ni ? acc1 : acc0;
#pragma unroll
            for (int reg = 0; reg < 16; ++reg) {
                const int row = n0 + wr * 32 + 4 * lhalf + (reg & 3) + 8 * (reg >> 2);
                if (row < NN) {
                    const float v = fmaxf(a[reg] + bv, 0.f);
                    hout[(size_t)row * 128 + col] = f2bf(v);
                }
            }
        }
    } else {
        // ---- layer 2 epilogue: fused head out[n] = relu(h).Wout + bout ----
        const int col0 = wc * 64 + l31;
        const int col1 = col0 + 32;
        const float bv0 = bias[col0], bv1 = bias[col1];
        const float wo0 = Wout[col0], wo1 = Wout[col1];
        float part[16];
#pragma unroll
        for (int reg = 0; reg < 16; ++reg) {
            part[reg] = fmaxf(acc0[reg] + bv0, 0.f) * wo0
                      + fmaxf(acc1[reg] + bv1, 0.f) * wo1;
#pragma unroll
            for (int m = 16; m > 0; m >>= 1)
                part[reg] += __shfl_xor(part[reg], m, 64);
        }
        __syncthreads();                        // smem free for reuse
        float* hsum = (float*)smem;             // [2][64]
        if (l31 == 0) {
#pragma unroll
            for (int reg = 0; reg < 16; ++reg) {
                const int rl = wr * 32 + 4 * lhalf + (reg & 3) + 8 * (reg >> 2);
                hsum[wc * 64 + rl] = part[reg];
            }
        }
        __syncthreads();
        if (t < 64) {
            const int row = n0 + t;
            if (row < NN) outp[row] = hsum[t] + hsum[64 + t] + bout[0];
        }
    }
}

extern "C" void kernel_launch(void* const* d_in, const int* in_sizes, int n_in,
                              void* d_out, int out_size, void* d_ws, size_t ws_size,
                              hipStream_t stream) {
    const float* x     = (const float*)d_in[0];
    const int*   eidx  = (const int*)  d_in[1];
    const int*   etype = (const int*)  d_in[2];
    const float* W1    = (const float*)d_in[3];
    const float* root1 = (const float*)d_in[4];
    const float* b1    = (const float*)d_in[5];
    const float* W2    = (const float*)d_in[6];
    const float* root2 = (const float*)d_in[7];
    const float* b2    = (const float*)d_in[8];
    const float* Wout  = (const float*)d_in[9];
    const float* bout  = (const float*)d_in[10];
    float* out = (float*)d_out;

    const int* src = eidx;
    const int* dst = eidx + EE;

    char* ws = (char*)d_ws;
    size_t pos = 0;
    auto take = [&](size_t bytes) {
        char* p = ws + pos;
        pos = (pos + bytes + 255) & ~(size_t)255;
        return p;
    };
    int*    ghist  = (int*)   take((size_t)NCB * 4);
    int*    gstart = (int*)   take((size_t)(NCB + 1) * 4);
    int*    gcur   = (int*)   take((size_t)NCB * 4);
    uint*   packed = (uint*)  take((size_t)EE * 4);
    int*    off    = (int*)   take((size_t)(NB + 1) * 4);
    int*    srcs   = (int*)   take((size_t)EE * 4);
    ushort* xb     = (ushort*)take((size_t)NN * 128 * 2);
    ushort* h1     = (ushort*)take((size_t)NN * 128 * 2);
    ushort* agg    = (ushort*)take((size_t)NN * 1024 * 2);
    ushort* Bt1    = (ushort*)take((size_t)128 * 1152 * 2);
    ushort* Bt2    = (ushort*)take((size_t)128 * 1152 * 2);
    (void)ws_size; (void)n_in; (void)in_sizes; (void)out_size;

    const int wblocks = (NN + 3) / 4;               // 12500 wave-per-node
    const int gblocks = (NN + 63) / 64;             // 782 GEMM tiles

    hipMemsetAsync(ghist, 0, (size_t)NCB * 4, stream);
    chist_kernel<<<PBLK, 1024, 0, stream>>>(dst, ghist);
    cscan_kernel<<<1, 256, 0, stream>>>(ghist, gstart, gcur);
    cpart_kernel<<<PBLK, 1024, 0, stream>>>(src, dst, etype, gcur, packed);
    fsort_kernel<<<NCB, 1024, 0, stream>>>(gstart, packed, off, srcs);
    prep_w_kernel<<<dim3(128, 2), 256, 0, stream>>>(root1, W1, root2, W2, Bt1, Bt2);
    cvt_x_kernel <<<3125, 256, 0, stream>>>(x, xb);

    // layer 1
    agg_kernel<<<wblocks, 256, 0, stream>>>(off, srcs, xb, agg);
    gemm_mfma <<<gblocks, 256, 0, stream>>>(xb, agg, Bt1, b1, h1,
                                            nullptr, nullptr, nullptr);
    // layer 2 (+ fused head)
    agg_kernel<<<wblocks, 256, 0, stream>>>(off, srcs, h1, agg);
    gemm_mfma <<<gblocks, 256, 0, stream>>>(h1, agg, Bt2, b2, nullptr,
                                            Wout, bout, out);
}

// Round 17
// 202.384 us; speedup vs baseline: 1.0737x; 1.0737x over previous
//
#include <hip/hip_runtime.h>
#include <hip/hip_bf16.h>

// RGCN regression: N=50000, E=800000, R=8, C=H=128.
// Round 17: EXACT REVERT to R15 (202us best). R16's nontemporal agg stores
// moved agg to HBM and starved the GEMM's warm-L2 reads (gemm 40->50us,
// net 217us). The 85MB agg "over-fetch" was the gemm's cache supply, not
// waste. Final configuration:
//  1) 2-level MSD partition sort by (dst,rel)
//  2) cvt x -> bf16; weights -> Bt[n][k] bf16
//  3) per layer: wave-per-node agg, 8 rel-groups x 8 lanes, row-pipelined
//  4) layer1 gemm -> h1; layer2 gemm -> out (fused head from fp32 accs)

constexpr int NN = 50000;
constexpr int EE = 800000;
constexpr int NB = NN * 8;            // 400000 (dst,rel) buckets
constexpr int NCB = (NN + 255) >> 8;  // 196 coarse buckets
constexpr int EPB = 8192;             // edges per partition block
constexpr int PBLK = (EE + EPB - 1) / EPB;   // 98
constexpr int NSB = 2048;             // sub-buckets per coarse bucket

typedef __attribute__((ext_vector_type(8))) short bf16x8;
typedef __attribute__((ext_vector_type(16))) float f32x16;
typedef __attribute__((address_space(3))) uint32_t lds_u32;
typedef __attribute__((address_space(1))) const uint32_t glb_u32;

static __device__ __forceinline__ ushort f2bf(float f) {
    uint u = __float_as_uint(f);
    uint r = (u + 0x7fffu + ((u >> 16) & 1u)) >> 16;   // RTNE
    return (ushort)r;
}
static __device__ __forceinline__ float bflo(uint v) { return __uint_as_float(v << 16); }
static __device__ __forceinline__ float bfhi(uint v) { return __uint_as_float(v & 0xffff0000u); }

static __device__ __forceinline__ void stage16(const void* g, void* lds) {
    __builtin_amdgcn_global_load_lds((glb_u32*)g, (lds_u32*)lds, 16, 0, 0);
}

// ---------------- P1: coarse histogram (dst>>8), LDS-aggregated ----------------
__global__ __launch_bounds__(1024) void chist_kernel(const int* __restrict__ dst,
                                                     int* __restrict__ ghist) {
    __shared__ int h[NCB];
    const int t = threadIdx.x;
    for (int i = t; i < NCB; i += 1024) h[i] = 0;
    __syncthreads();
    const int e0 = blockIdx.x * EPB + t;
#pragma unroll
    for (int jj = 0; jj < 8; ++jj) {
        const int e = e0 + jj * 1024;
        if (e < EE) atomicAdd(&h[dst[e] >> 8], 1);
    }
    __syncthreads();
    for (int i = t; i < NCB; i += 1024)
        if (h[i]) atomicAdd(&ghist[i], h[i]);
}

// ---------------- P2: scan 196 coarse totals ----------------
__global__ __launch_bounds__(256) void cscan_kernel(const int* __restrict__ ghist,
                                                    int* __restrict__ gstart,
                                                    int* __restrict__ gcur) {
    __shared__ int sm[256];
    const int t = threadIdx.x;
    const int v = (t < NCB) ? ghist[t] : 0;
    sm[t] = v;
    __syncthreads();
    for (int d = 1; d < 256; d <<= 1) {
        int u = (t >= d) ? sm[t - d] : 0;
        __syncthreads();
        sm[t] += u;
        __syncthreads();
    }
    const int excl = sm[t] - v;
    if (t < NCB) { gstart[t] = excl; gcur[t] = excl; }
    if (t == NCB - 1) gstart[NCB] = excl + v;   // == EE
}

// ---------------- P3: coarse partition, block-reserved ranges ----------------
// packed = (dlow<<19) | (et<<16) | src
__global__ __launch_bounds__(1024) void cpart_kernel(const int* __restrict__ src,
                                                     const int* __restrict__ dst,
                                                     const int* __restrict__ et,
                                                     int* __restrict__ gcur,
                                                     uint* __restrict__ packed) {
    __shared__ int h[NCB];
    const int t = threadIdx.x;
    for (int i = t; i < NCB; i += 1024) h[i] = 0;
    __syncthreads();
    const int e0 = blockIdx.x * EPB + t;
    int myb[8]; uint mydat[8];
#pragma unroll
    for (int jj = 0; jj < 8; ++jj) {
        const int e = e0 + jj * 1024;
        if (e < EE) {
            const int d = dst[e];
            myb[jj] = d >> 8;
            mydat[jj] = (uint)src[e] | ((uint)et[e] << 16) | ((uint)(d & 255) << 19);
            atomicAdd(&h[myb[jj]], 1);
        } else myb[jj] = -1;
    }
    __syncthreads();
    for (int i = t; i < NCB; i += 1024)
        h[i] = h[i] ? atomicAdd(&gcur[i], h[i]) : 0;   // h becomes running cursor
    __syncthreads();
#pragma unroll
    for (int jj = 0; jj < 8; ++jj) {
        if (myb[jj] >= 0) {
            const int pos = atomicAdd(&h[myb[jj]], 1);
            packed[pos] = mydat[jj];
        }
    }
}

// ---------------- P4: per-coarse-bucket fine sort -> off[] + srcs[] ----------------
__global__ __launch_bounds__(1024) void fsort_kernel(const int* __restrict__ gstart,
                                                     const uint* __restrict__ packed,
                                                     int* __restrict__ off,
                                                     int* __restrict__ srcs) {
    __shared__ int hist[NSB];
    __shared__ int scn[NSB];
    __shared__ int h2[1024];
    const int b = blockIdx.x;
    const int t = threadIdx.x;
    const int s = gstart[b], e = gstart[b + 1];

    for (int i = t; i < NSB; i += 1024) hist[i] = 0;
    __syncthreads();
    for (int i = s + t; i < e; i += 1024)
        atomicAdd(&hist[(packed[i] >> 16) & 0x7FF], 1);
    __syncthreads();
    const int a0 = hist[2 * t], a1 = hist[2 * t + 1];
    h2[t] = a0 + a1;
    __syncthreads();
    for (int d = 1; d < 1024; d <<= 1) {
        int u = (t >= d) ? h2[t - d] : 0;
        __syncthreads();
        h2[t] += u;
        __syncthreads();
    }
    const int base = h2[t] - (a0 + a1);
    scn[2 * t] = base;
    scn[2 * t + 1] = base + a0;
    __syncthreads();
    const int gsubbase = b << 11;
    for (int i = t; i < NSB; i += 1024) {
        const int g = gsubbase + i;
        if (g < NB) off[g] = s + scn[i];
    }
    if (b == NCB - 1 && t == 0) off[NB] = EE;
    __syncthreads();
    for (int i = s + t; i < e; i += 1024) {
        const uint k = packed[i];
        const int pos = atomicAdd(&scn[(k >> 16) & 0x7FF], 1);
        srcs[s + pos] = (int)(k & 0xFFFF);
    }
}

// ---------------- x fp32 -> bf16 ----------------
__global__ __launch_bounds__(256) void cvt_x_kernel(const float* __restrict__ x,
                                                    ushort* __restrict__ xb) {
    const int tid = blockIdx.x * blockDim.x + threadIdx.x;
    const size_t i = (size_t)tid * 8;
    const float4 v0 = *reinterpret_cast<const float4*>(x + i);
    const float4 v1 = *reinterpret_cast<const float4*>(x + i + 4);
    uint4 o;
    o.x = (uint)f2bf(v0.x) | ((uint)f2bf(v0.y) << 16);
    o.y = (uint)f2bf(v0.z) | ((uint)f2bf(v0.w) << 16);
    o.z = (uint)f2bf(v1.x) | ((uint)f2bf(v1.y) << 16);
    o.w = (uint)f2bf(v1.z) | ((uint)f2bf(v1.w) << 16);
    *reinterpret_cast<uint4*>(xb + i) = o;
}

// ---------------- weights -> Bt[n][k] bf16, k = [root(128) | W(1024)] ----------------
__global__ __launch_bounds__(256) void prep_w_kernel(const float* __restrict__ root1,
                                                     const float* __restrict__ W1,
                                                     const float* __restrict__ root2,
                                                     const float* __restrict__ W2,
                                                     ushort* __restrict__ Bt1,
                                                     ushort* __restrict__ Bt2) {
    const float* root = blockIdx.y ? root2 : root1;
    const float* W    = blockIdx.y ? W2 : W1;
    ushort* Bt        = blockIdx.y ? Bt2 : Bt1;
    const int n = blockIdx.x;
    for (int k = threadIdx.x; k < 1152; k += 256) {
        float v = (k < 128) ? root[(size_t)k * 128 + n]
                            : W[(size_t)(k - 128) * 128 + n];
        Bt[(size_t)n * 1152 + k] = f2bf(v);
    }
}

// ---------------- aggregation: wave per node, 8 segments parallel, PIPELINED ----
// lane = g*8 + j. Index prefetch 2 ahead; feature-row prefetch 1 ahead, so the
// next row's 2x dwordx4 issue BEFORE this row's 32-op accumulate.
__global__ __launch_bounds__(256) void agg_kernel(const int* __restrict__ off,
                                                  const int* __restrict__ srcs,
                                                  const ushort* __restrict__ feat,
                                                  ushort* __restrict__ agg) {
    const int wid = (blockIdx.x * blockDim.x + threadIdx.x) >> 6;
    if (wid >= NN) return;
    const int lane = threadIdx.x & 63;
    const int g = lane >> 3;            // relation group 0..7
    const int j = lane & 7;             // 16-ushort chunk within row

    const int s1 = off[wid * 8 + g + 1];
    int i = off[wid * 8 + g];
    const int cnt = s1 - i;

    float a[16];
#pragma unroll
    for (int k = 0; k < 16; ++k) a[k] = 0.f;

    const size_t jb = (size_t)(j << 4);
    int p  = (i < s1)     ? srcs[i]     : 0;
    int pn = (i + 1 < s1) ? srcs[i + 1] : 0;
    const uint4* rp = reinterpret_cast<const uint4*>(feat + (size_t)p * 128 + jb);
    uint4 v0 = rp[0], v1 = rp[1];       // current row (empty-seg lanes read row 0: harmless)

    while (__any(i < s1)) {
        const int pnn = (i + 2 < s1) ? srcs[i + 2] : 0;     // index prefetch, 2 ahead
        const uint4* rn = reinterpret_cast<const uint4*>(feat + (size_t)pn * 128 + jb);
        const uint4 w0 = rn[0], w1 = rn[1];                 // row prefetch, 1 ahead
        if (i < s1) {
            a[0] += bflo(v0.x);  a[1] += bfhi(v0.x);
            a[2] += bflo(v0.y);  a[3] += bfhi(v0.y);
            a[4] += bflo(v0.z);  a[5] += bfhi(v0.z);
            a[6] += bflo(v0.w);  a[7] += bfhi(v0.w);
            a[8] += bflo(v1.x);  a[9] += bfhi(v1.x);
            a[10] += bflo(v1.y); a[11] += bfhi(v1.y);
            a[12] += bflo(v1.z); a[13] += bfhi(v1.z);
            a[14] += bflo(v1.w); a[15] += bfhi(v1.w);
        }
        v0 = w0; v1 = w1;
        p = pn; pn = pnn;
        ++i;
    }

    const float inv = 1.0f / (float)max(cnt, 1);
    uint4 o0, o1;
    o0.x = (uint)f2bf(a[0] * inv)  | ((uint)f2bf(a[1] * inv)  << 16);
    o0.y = (uint)f2bf(a[2] * inv)  | ((uint)f2bf(a[3] * inv)  << 16);
    o0.z = (uint)f2bf(a[4] * inv)  | ((uint)f2bf(a[5] * inv)  << 16);
    o0.w = (uint)f2bf(a[6] * inv)  | ((uint)f2bf(a[7] * inv)  << 16);
    o1.x = (uint)f2bf(a[8] * inv)  | ((uint)f2bf(a[9] * inv)  << 16);
    o1.y = (uint)f2bf(a[10] * inv) | ((uint)f2bf(a[11] * inv) << 16);
    o1.z = (uint)f2bf(a[12] * inv) | ((uint)f2bf(a[13] * inv) << 16);
    o1.w = (uint)f2bf(a[14] * inv) | ((uint)f2bf(a[15] * inv) << 16);
    ushort* o = agg + (size_t)wid * 1024 + g * 128 + (j << 4);
    reinterpret_cast<uint4*>(o)[0] = o0;
    reinterpret_cast<uint4*>(o)[1] = o1;
}

// ---------------- MFMA GEMM: h = relu(bias + [xb|agg] @ Bt^T) ----------------
// A logical [N, 1152] bf16, Bt [128][1152] bf16. Block: 4 waves (2x2),
// tile 64(M) x 128(N), BK=64, 2-phase dbuf (R6, measured best).
// If outp != nullptr (layer 2): fused head — out[n] = relu(h[n]).Wout + bout
// computed from fp32 accs (shfl butterfly + LDS cross-wave add); hout unused.
__global__ __launch_bounds__(256) void gemm_mfma(const ushort* __restrict__ xb,
                                                 const ushort* __restrict__ agg,
                                                 const ushort* __restrict__ Bt,
                                                 const float* __restrict__ bias,
                                                 ushort* __restrict__ hout,
                                                 const float* __restrict__ Wout,
                                                 const float* __restrict__ bout,
                                                 float* __restrict__ outp) {
    __shared__ __align__(16) uint8_t smem[49152];
    const int t = threadIdx.x;
    const int lane = t & 63;
    const int w = t >> 6;
    const int wr = w >> 1, wc = w & 1;
    const int n0 = blockIdx.x * 64;
    const int l31 = lane & 31;
    const int lhalf = lane >> 5;

    f32x16 acc0, acc1;
#pragma unroll
    for (int r = 0; r < 16; ++r) { acc0[r] = 0.f; acc1[r] = 0.f; }

    const int rA = wr * 32 + l31;
    const int aoff = rA * 128, aswz = (rA & 7) << 4;
    const int nB0 = wc * 64 + l31;
    const int nB1 = nB0 + 32;
    const int boff0 = 8192 + nB0 * 128, bswz0 = (nB0 & 7) << 4;
    const int boff1 = 8192 + nB1 * 128, bswz1 = (nB1 & 7) << 4;
    const int ckb = lhalf << 4;

    const int rsub = lane >> 3;
    const int srcChunk = (((lane & 7) ^ (lane >> 3)) << 4);
    int garowA[2];
#pragma unroll
    for (int jj = 0; jj < 2; ++jj)
        garowA[jj] = min(n0 + 16 * w + 8 * jj + rsub, NN - 1);
    size_t bOffG[4];
#pragma unroll
    for (int jj = 0; jj < 4; ++jj)
        bOffG[jj] = (size_t)(32 * w + 8 * jj + rsub) * 2304 + srcChunk;

    const uint8_t* xb8  = (const uint8_t*)xb;
    const uint8_t* agg8 = (const uint8_t*)agg;
    const uint8_t* Bt8  = (const uint8_t*)Bt;

    auto STAGE = [&](int buf, int kt) {
        uint8_t* base = smem + buf * 24576;
        const uint8_t* Asrc; int shift, koffB;
        if (kt < 2) { Asrc = xb8;  shift = 8;  koffB = kt * 128; }
        else        { Asrc = agg8; shift = 11; koffB = (kt - 2) * 128; }
#pragma unroll
        for (int jj = 0; jj < 2; ++jj)
            stage16(Asrc + (((size_t)garowA[jj]) << shift) + koffB + srcChunk,
                    base + (2 * w + jj) * 1024);
#pragma unroll
        for (int jj = 0; jj < 4; ++jj)
            stage16(Bt8 + bOffG[jj] + kt * 128,
                    base + 8192 + (4 * w + jj) * 1024);
    };

    auto COMPUTE = [&](int buf) {
        const uint8_t* base = smem + buf * 24576;
#pragma unroll
        for (int kb = 0; kb < 4; ++kb) {
            const int cb = kb * 32 + ckb;
            const bf16x8 af = *reinterpret_cast<const bf16x8*>(base + aoff  + (cb ^ aswz));
            const bf16x8 b0 = *reinterpret_cast<const bf16x8*>(base + boff0 + (cb ^ bswz0));
            const bf16x8 b1 = *reinterpret_cast<const bf16x8*>(base + boff1 + (cb ^ bswz1));
            acc0 = __builtin_amdgcn_mfma_f32_32x32x16_bf16(af, b0, acc0, 0, 0, 0);
            acc1 = __builtin_amdgcn_mfma_f32_32x32x16_bf16(af, b1, acc1, 0, 0, 0);
        }
    };

    STAGE(0, 0);
    __syncthreads();
    int cur = 0;
#pragma unroll 1
    for (int kt = 0; kt < 17; ++kt) {
        STAGE(cur ^ 1, kt + 1);
        COMPUTE(cur);
        __syncthreads();
        cur ^= 1;
    }
    COMPUTE(cur);

    if (outp == nullptr) {
        // ---- layer 1 epilogue: write bf16 h ----
#pragma unroll
        for (int ni = 0; ni < 2; ++ni) {
            const int col = wc * 64 + ni * 32 + l31;
            const float bv = bias[col];
            const f32x16& a = ni ? acc1 : acc0;
#pragma unroll
            for (int reg = 0; reg < 16; ++reg) {
                const int row = n0 + wr * 32 + 4 * lhalf + (reg & 3) + 8 * (reg >> 2);
                if (row < NN) {
                    const float v = fmaxf(a[reg] + bv, 0.f);
                    hout[(size_t)row * 128 + col] = f2bf(v);
                }
            }
        }
    } else {
        // ---- layer 2 epilogue: fused head out[n] = relu(h).Wout + bout ----
        const int col0 = wc * 64 + l31;
        const int col1 = col0 + 32;
        const float bv0 = bias[col0], bv1 = bias[col1];
        const float wo0 = Wout[col0], wo1 = Wout[col1];
        float part[16];
#pragma unroll
        for (int reg = 0; reg < 16; ++reg) {
            part[reg] = fmaxf(acc0[reg] + bv0, 0.f) * wo0
                      + fmaxf(acc1[reg] + bv1, 0.f) * wo1;
#pragma unroll
            for (int m = 16; m > 0; m >>= 1)
                part[reg] += __shfl_xor(part[reg], m, 64);
        }
        __syncthreads();                        // smem free for reuse
        float* hsum = (float*)smem;             // [2][64]
        if (l31 == 0) {
#pragma unroll
            for (int reg = 0; reg < 16; ++reg) {
                const int rl = wr * 32 + 4 * lhalf + (reg & 3) + 8 * (reg >> 2);
                hsum[wc * 64 + rl] = part[reg];
            }
        }
        __syncthreads();
        if (t < 64) {
            const int row = n0 + t;
            if (row < NN) outp[row] = hsum[t] + hsum[64 + t] + bout[0];
        }
    }
}

extern "C" void kernel_launch(void* const* d_in, const int* in_sizes, int n_in,
                              void* d_out, int out_size, void* d_ws, size_t ws_size,
                              hipStream_t stream) {
    const float* x     = (const float*)d_in[0];
    const int*   eidx  = (const int*)  d_in[1];
    const int*   etype = (const int*)  d_in[2];
    const float* W1    = (const float*)d_in[3];
    const float* root1 = (const float*)d_in[4];
    const float* b1    = (const float*)d_in[5];
    const float* W2    = (const float*)d_in[6];
    const float* root2 = (const float*)d_in[7];
    const float* b2    = (const float*)d_in[8];
    const float* Wout  = (const float*)d_in[9];
    const float* bout  = (const float*)d_in[10];
    float* out = (float*)d_out;

    const int* src = eidx;
    const int* dst = eidx + EE;

    char* ws = (char*)d_ws;
    size_t pos = 0;
    auto take = [&](size_t bytes) {
        char* p = ws + pos;
        pos = (pos + bytes + 255) & ~(size_t)255;
        return p;
    };
    int*    ghist  = (int*)   take((size_t)NCB * 4);
    int*    gstart = (int*)   take((size_t)(NCB + 1) * 4);
    int*    gcur   = (int*)   take((size_t)NCB * 4);
    uint*   packed = (uint*)  take((size_t)EE * 4);
    int*    off    = (int*)   take((size_t)(NB + 1) * 4);
    int*    srcs   = (int*)   take((size_t)EE * 4);
    ushort* xb     = (ushort*)take((size_t)NN * 128 * 2);
    ushort* h1     = (ushort*)take((size_t)NN * 128 * 2);
    ushort* agg    = (ushort*)take((size_t)NN * 1024 * 2);
    ushort* Bt1    = (ushort*)take((size_t)128 * 1152 * 2);
    ushort* Bt2    = (ushort*)take((size_t)128 * 1152 * 2);
    (void)ws_size; (void)n_in; (void)in_sizes; (void)out_size;

    const int wblocks = (NN + 3) / 4;               // 12500 wave-per-node
    const int gblocks = (NN + 63) / 64;             // 782 GEMM tiles

    hipMemsetAsync(ghist, 0, (size_t)NCB * 4, stream);
    chist_kernel<<<PBLK, 1024, 0, stream>>>(dst, ghist);
    cscan_kernel<<<1, 256, 0, stream>>>(ghist, gstart, gcur);
    cpart_kernel<<<PBLK, 1024, 0, stream>>>(src, dst, etype, gcur, packed);
    fsort_kernel<<<NCB, 1024, 0, stream>>>(gstart, packed, off, srcs);
    prep_w_kernel<<<dim3(128, 2), 256, 0, stream>>>(root1, W1, root2, W2, Bt1, Bt2);
    cvt_x_kernel <<<3125, 256, 0, stream>>>(x, xb);

    // layer 1
    agg_kernel<<<wblocks, 256, 0, stream>>>(off, srcs, xb, agg);
    gemm_mfma <<<gblocks, 256, 0, stream>>>(xb, agg, Bt1, b1, h1,
                                            nullptr, nullptr, nullptr);
    // layer 2 (+ fused head)
    agg_kernel<<<wblocks, 256, 0, stream>>>(off, srcs, h1, agg);
    gemm_mfma <<<gblocks, 256, 0, stream>>>(h1, agg, Bt2, b2, nullptr,
                                            Wout, bout, out);
}